// Round 1
// baseline (197.464 us; speedup 1.0000x reference)
//
#include <hip/hip_runtime.h>

#define NN 100
#define CC 256
#define NKK 103
#define LSA 72     // Abuf stride (bf16): 144 B rows, 16B-aligned frags, 2-way bank alias (free)
#define LDPW 136   // PW stride (bf16): 272 B rows, 16B-aligned frags
#define OTS 260    // out-transpose stride (f32): 1040 B rows, 16B-aligned

typedef __bf16 bf16;
typedef __bf16 bf16x4 __attribute__((ext_vector_type(4)));
typedef __bf16 bf16x8 __attribute__((ext_vector_type(8)));
typedef float f32x4 __attribute__((ext_vector_type(4)));

// kernel0: W (f32 [256][103]) -> Wt (bf16 [103][256]) in workspace.
// Removes per-block W scatter (scalar loads + div/mod + 8-way LDS bank conflicts).
__global__ void wl_transpose(const float* __restrict__ W, bf16* __restrict__ Wt)
{
    int idx = blockIdx.x * 256 + threadIdx.x;
    if (idx < NKK * CC) {
        int ka = idx >> 8;      // /256
        int k  = idx & 255;
        Wt[ka * CC + k] = (bf16)W[k * NKK + ka];
    }
}

// SMEM layout (manually carved so phase-D OT can alias dead phase-A/B buffers):
// [    0, 27200)  PW   bf16 [100][136]
// [27200, 41600)  Abuf bf16 [100][72]
// [41600, 42800)  DW   f32  [100][3]
// [42800, 49200)  RP   f32  [8][100][2]
// [49200, 50000)  RS   f32  [100][2]
// phase D: OT f32 [40][260] aliases [0, 41600)  (PW+Abuf dead by then; 39*260+256 f32 = 41584 B)
__global__ __launch_bounds__(512, 4)
void dysepconv_fused(const float* __restrict__ query,
                     const float* __restrict__ value,
                     const bf16*  __restrict__ Wt,
                     const float* __restrict__ bwl,
                     const float* __restrict__ gamma,
                     const float* __restrict__ beta,
                     float* __restrict__ out)
{
    __shared__ __align__(16) char SMEM[50000];
    bf16*  PW   = (bf16*)SMEM;
    bf16*  Abuf = (bf16*)(SMEM + 27200);
    float (*DW)[3]      = (float(*)[3])(SMEM + 41600);
    float (*RP)[NN][2]  = (float(*)[NN][2])(SMEM + 42800);
    float (*RS)[2]      = (float(*)[2])(SMEM + 49200);
    float* OT = (float*)SMEM;

    const int t    = threadIdx.x;
    const int w    = t >> 6;          // wave 0..7
    const int lane = t & 63;
    const int ln16 = lane & 15;
    const int g    = lane >> 4;
    const int hi8  = g * 8;
    const int b    = blockIdx.x;
    const int cb   = w * 16 + ln16;   // channel (phase B/D)

    const float* qb = query + (size_t)b * NN * CC;
    const float* vb = value + (size_t)b * NN * CC;

    // ---------------- Phase A: dy = q @ W + bias ----------------
    f32x4 acc1[7];
    #pragma unroll
    for (int I = 0; I < 7; ++I) acc1[I] = (f32x4){0.f, 0.f, 0.f, 0.f};

    // hoist all W fragments into registers (L2-hot 53 KB, shared by all blocks)
    const int rB = (w * 16 + ln16 < NKK) ? (w * 16 + ln16) : (NKK - 1); // clamp: cols>=103 discarded
    bf16x8 wfrag[4][2];
    #pragma unroll
    for (int kc = 0; kc < 4; ++kc)
        #pragma unroll
        for (int s = 0; s < 2; ++s)
            wfrag[kc][s] = *(const bf16x8*)(Wt + rB * CC + kc * 64 + s * 32 + hi8);

    // q chunk 0 into regs
    f32x4 qv[4];
    #pragma unroll
    for (int p = 0; p < 4; ++p) {
        int idx = p * 512 + t;
        if (idx < 1600) {
            int r = idx >> 4, j = (idx & 15) << 2;
            qv[p] = *(const f32x4*)(qb + r * CC + j);
        }
    }

    #pragma unroll
    for (int kc = 0; kc < 4; ++kc) {
        if (kc) __syncthreads();               // prior chunk's Abuf MFMA reads done
        #pragma unroll
        for (int p = 0; p < 4; ++p) {
            int idx = p * 512 + t;
            if (idx < 1600) {
                int r = idx >> 4, j = (idx & 15) << 2;
                bf16x4 s;
                #pragma unroll
                for (int i = 0; i < 4; ++i) s[i] = (bf16)qv[p][i];
                *(bf16x4*)&Abuf[r * LSA + j] = s;
            }
        }
        f32x4 qn[4];
        if (kc < 3) {                          // prefetch next chunk; drains under MFMA+barrier
            #pragma unroll
            for (int p = 0; p < 4; ++p) {
                int idx = p * 512 + t;
                if (idx < 1600) {
                    int r = idx >> 4, j = (idx & 15) << 2;
                    qn[p] = *(const f32x4*)(qb + r * CC + (kc + 1) * 64 + j);
                }
            }
        }
        __syncthreads();                       // Abuf ready

        if (w < 7) {
            #pragma unroll
            for (int s = 0; s < 2; ++s) {
                bf16x8 bv = wfrag[kc][s];
                #pragma unroll
                for (int I = 0; I < 7; ++I) {
                    int row = I * 16 + ln16;
                    row = (row < NN) ? row : (NN - 1);   // clamp: rows>=100 discarded
                    bf16x8 av = *(const bf16x8*)&Abuf[row * LSA + s * 32 + hi8];
                    acc1[I] = __builtin_amdgcn_mfma_f32_16x16x32_bf16(av, bv, acc1[I], 0, 0, 0);
                }
            }
        }
        if (kc < 3) {
            #pragma unroll
            for (int p = 0; p < 4; ++p) qv[p] = qn[p];
        }
    }
    // no barrier here: epilogue writes PW/DW (disjoint from Abuf); visibility via the sync below.

    // epilogue A: zero PW k-pad cols (must be exact 0), write pw (bf16) / dw (fp32)
    for (int i = t; i < NN * 28; i += 512) {
        int r = i / 28, m = 100 + (i - (i / 28) * 28);
        PW[r * LDPW + m] = (bf16)0.f;
    }
    // prefetch value loads for ks=0 (latency hides under epilogue + barrier)
    float xv[8], yv[8];
    #pragma unroll
    for (int j = 0; j < 8; ++j) {
        int m = hi8 + j;                       // ks=0: m < 32 < NN always
        const float* vr = vb + m * CC;
        xv[j] = vr[cb];
        yv[j] = vr[cb + 128];
    }
    if (w < 7) {
        const int kap = w * 16 + ln16;
        const float bw = (kap < NKK) ? bwl[kap] : 0.f;
        #pragma unroll
        for (int I = 0; I < 7; ++I) {
            #pragma unroll
            for (int r = 0; r < 4; ++r) {
                int n = I * 16 + g * 4 + r;
                if (n < NN && kap < NKK) {
                    float v = acc1[I][r] + bw;
                    if (kap < 3) DW[n][kap] = v;
                    else         PW[n * LDPW + (kap - 3)] = (bf16)v;
                }
            }
        }
    }
    __syncthreads();   // PW/DW visible

    // ---------------- Phase B/C: conv (register layout, pipelined loads) + GEMM2 ----------------
    f32x4 acc2[2][7];
    #pragma unroll
    for (int st = 0; st < 2; ++st)
        #pragma unroll
        for (int I = 0; I < 7; ++I) acc2[st][I] = (f32x4){0.f, 0.f, 0.f, 0.f};

    #pragma unroll
    for (int ks = 0; ks < 4; ++ks) {
        float xn[8], yn[8];
        if (ks < 3) {                           // issue next-ks loads before the shfl/conv chain
            #pragma unroll
            for (int j = 0; j < 8; ++j) {
                int m = (ks + 1) * 32 + hi8 + j;
                bool mv = (m < NN);
                const float* vr = vb + m * CC;
                xn[j] = mv ? vr[cb]       : 0.f;
                yn[j] = mv ? vr[cb + 128] : 0.f;
            }
        }
        bf16x8 dv0, dv1;
        #pragma unroll
        for (int j = 0; j < 8; ++j) {
            int  m  = ks * 32 + hi8 + j;
            bool mv = (m < NN);
            int  mc = mv ? m : (NN - 1);
            float w0 = DW[mc][0], w1 = DW[mc][1], w2 = DW[mc][2];
            float x0 = xv[j], y0 = yv[j];
            float xm = __shfl(x0, (lane - 1) & 63), xp = __shfl(x0, (lane + 1) & 63);
            float ym = __shfl(y0, (lane - 1) & 63), yp = __shfl(y0, (lane + 1) & 63);
            if (ln16 == 0) {
                xm = (mv && cb > 0) ? vb[m * CC + cb - 1] : 0.f;
                ym = mv ? vb[m * CC + cb + 127] : 0.f;
            }
            if (ln16 == 15) {
                xp = mv ? vb[m * CC + cb + 1] : 0.f;
                yp = (mv && cb + 129 < CC) ? vb[m * CC + cb + 129] : 0.f;
            }
            float d0 = w0 * xm + w1 * x0 + w2 * xp;
            float d1 = w0 * ym + w1 * y0 + w2 * yp;
            dv0[j] = (bf16)(mv ? fmaxf(d0, 0.f) : 0.f);
            dv1[j] = (bf16)(mv ? fmaxf(d1, 0.f) : 0.f);
        }
        #pragma unroll
        for (int I = 0; I < 7; ++I) {
            int row = I * 16 + ln16;
            row = (row < NN) ? row : (NN - 1);   // PW has 100 rows; clamped rows discarded
            bf16x8 af = *(const bf16x8*)&PW[row * LDPW + ks * 32 + hi8];
            acc2[0][I] = __builtin_amdgcn_mfma_f32_16x16x32_bf16(af, dv0, acc2[0][I], 0, 0, 0);
            acc2[1][I] = __builtin_amdgcn_mfma_f32_16x16x32_bf16(af, dv1, acc2[1][I], 0, 0, 0);
        }
        if (ks < 3) {
            #pragma unroll
            for (int j = 0; j < 8; ++j) { xv[j] = xn[j]; yv[j] = yn[j]; }
        }
    }

    // prefetch LN affine params (L2-hot) before the reduction barriers
    const float gm0 = gamma[cb], gm1 = gamma[cb + 128];
    const float bt0 = beta[cb],  bt1 = beta[cb + 128];

    // ---------------- Phase D: LayerNorm ----------------
    #pragma unroll
    for (int I = 0; I < 7; ++I) {
        #pragma unroll
        for (int r = 0; r < 4; ++r) {
            float a = acc2[0][I][r], e = acc2[1][I][r];
            float s1 = a + e, s2 = a * a + e * e;
            #pragma unroll
            for (int mk = 1; mk < 16; mk <<= 1) {
                s1 += __shfl_xor(s1, mk);
                s2 += __shfl_xor(s2, mk);
            }
            int n = I * 16 + g * 4 + r;
            if (ln16 == 0 && n < NN) {
                RP[w][n][0] = s1;
                RP[w][n][1] = s2;
            }
        }
    }
    __syncthreads();
    if (t < NN) {
        float S1 = 0.f, S2 = 0.f;
        #pragma unroll
        for (int wi = 0; wi < 8; ++wi) { S1 += RP[wi][t][0]; S2 += RP[wi][t][1]; }
        float mu  = S1 * (1.f / 256.f);
        float var = S2 * (1.f / 256.f) - mu * mu;
        RS[t][0] = mu;
        RS[t][1] = rsqrtf(fmaxf(var, 0.f) + 1e-5f);
    }
    __syncthreads();   // after this, all GEMM2 PW reads are done -> OT may alias PW/Abuf

    // normalize + transpose through LDS in 3 chunks of 40 rows (5 barriers vs 14)
    float* ob = out + (size_t)b * NN * CC;
    #pragma unroll
    for (int h = 0; h < 3; ++h) {
        const int n0   = h * 40;
        const int rows = (h == 2) ? 20 : 40;
        #pragma unroll
        for (int I = 0; I < 7; ++I) {
            #pragma unroll
            for (int r = 0; r < 4; ++r) {
                int n = I * 16 + g * 4 + r;
                if (n >= n0 && n < n0 + rows) {
                    float mu = RS[n][0], rs = RS[n][1];
                    int rt = n - n0;
                    OT[rt * OTS + cb]       = (acc2[0][I][r] - mu) * rs * gm0 + bt0;
                    OT[rt * OTS + cb + 128] = (acc2[1][I][r] - mu) * rs * gm1 + bt1;
                }
            }
        }
        __syncthreads();
        #pragma unroll
        for (int p = 0; p < 5; ++p) {
            int idx = p * 512 + t;              // rows x 64 f32x4
            if (idx < rows * 64) {
                int row = idx >> 6, c4 = (idx & 63) << 2;
                *(f32x4*)(ob + (size_t)(n0 + row) * CC + c4) = *(const f32x4*)&OT[row * OTS + c4];
            }
        }
        if (h < 2) __syncthreads();
    }
}

extern "C" void kernel_launch(void* const* d_in, const int* in_sizes, int n_in,
                              void* d_out, int out_size, void* d_ws, size_t ws_size,
                              hipStream_t stream) {
    const float* query = (const float*)d_in[0];
    const float* value = (const float*)d_in[1];
    const float* W     = (const float*)d_in[2];
    const float* bwl   = (const float*)d_in[3];
    const float* gamma = (const float*)d_in[4];
    const float* beta  = (const float*)d_in[5];
    bf16* Wt = (bf16*)d_ws;   // 103*256*2 = 52736 B

    wl_transpose<<<dim3((NKK * CC + 255) / 256), dim3(256), 0, stream>>>(W, Wt);
    dysepconv_fused<<<dim3(512), dim3(512), 0, stream>>>(query, value, Wt, bwl, gamma, beta, (float*)d_out);
}

// Round 2
// 189.635 us; speedup vs baseline: 1.0413x; 1.0413x over previous
//
#include <hip/hip_runtime.h>

#define NN 100
#define CC 256
#define NKK 103
#define LSA 72     // Abuf stride (bf16): 144 B rows, 16B-aligned frags, 2-way bank alias (free)
#define LDPW 136   // PW stride (bf16): 272 B rows, 16B-aligned frags
#define OTS 260    // out-transpose stride (f32): 1040 B rows, 16B-aligned

typedef __bf16 bf16;
typedef __bf16 bf16x4 __attribute__((ext_vector_type(4)));
typedef __bf16 bf16x8 __attribute__((ext_vector_type(8)));
typedef float f32x4 __attribute__((ext_vector_type(4)));

// kernel0: W (f32 [256][103]) -> Wt (bf16 [103][256]) in workspace.
__global__ void wl_transpose(const float* __restrict__ W, bf16* __restrict__ Wt)
{
    int idx = blockIdx.x * 256 + threadIdx.x;
    if (idx < NKK * CC) {
        int ka = idx >> 8;      // /256
        int k  = idx & 255;
        Wt[ka * CC + k] = (bf16)W[k * NKK + ka];
    }
}

// SMEM layout (manually carved so phase-D OT can alias dead phase-A/B buffers):
// [    0, 27200)  PW   bf16 [100][136]
// [27200, 41600)  Abuf bf16 [100][72]
// [41600, 42800)  DW   f32  [100][3]
// [42800, 49200)  RP   f32  [8][100][2]
// [49200, 50000)  RS   f32  [100][2]
// phase D: OT f32 [40][260] aliases [0, 41600)  (PW+Abuf dead by then)
//
// Register budget: __launch_bounds__(512,4) => 128 unified VGPR+AGPR per wave.
// Phase A ~115 live, Phase B/C ~110, Phase D ~70 -- no scratch spills (round-1's
// wfrag[4][2] hoist + xn/yn prefetch blew this budget; both removed).
__global__ __launch_bounds__(512, 4)
void dysepconv_fused(const float* __restrict__ query,
                     const float* __restrict__ value,
                     const bf16*  __restrict__ Wt,
                     const float* __restrict__ bwl,
                     const float* __restrict__ gamma,
                     const float* __restrict__ beta,
                     float* __restrict__ out)
{
    __shared__ __align__(16) char SMEM[50000];
    bf16*  PW   = (bf16*)SMEM;
    bf16*  Abuf = (bf16*)(SMEM + 27200);
    float (*DW)[3]      = (float(*)[3])(SMEM + 41600);
    float (*RP)[NN][2]  = (float(*)[NN][2])(SMEM + 42800);
    float (*RS)[2]      = (float(*)[2])(SMEM + 49200);
    float* OT = (float*)SMEM;

    const int t    = threadIdx.x;
    const int w    = t >> 6;          // wave 0..7
    const int lane = t & 63;
    const int ln16 = lane & 15;
    const int g    = lane >> 4;
    const int hi8  = g * 8;
    const int b    = blockIdx.x;
    const int cb   = w * 16 + ln16;   // channel (phase B/D)

    const float* qb = query + (size_t)b * NN * CC;
    const float* vb = value + (size_t)b * NN * CC;

    // ---------------- Phase A: dy = q @ W + bias ----------------
    f32x4 acc1[7];
    #pragma unroll
    for (int I = 0; I < 7; ++I) acc1[I] = (f32x4){0.f, 0.f, 0.f, 0.f};

    const int rB = (w * 16 + ln16 < NKK) ? (w * 16 + ln16) : (NKK - 1); // clamp: cols>=103 discarded

    // q chunk 0 into regs
    f32x4 qv[4];
    #pragma unroll
    for (int p = 0; p < 4; ++p) {
        int idx = p * 512 + t;
        if (idx < 1600) {
            int r = idx >> 4, j = (idx & 15) << 2;
            qv[p] = *(const f32x4*)(qb + r * CC + j);
        }
    }

    #pragma unroll
    for (int kc = 0; kc < 4; ++kc) {
        if (kc) __syncthreads();               // prior chunk's Abuf MFMA reads done
        #pragma unroll
        for (int p = 0; p < 4; ++p) {
            int idx = p * 512 + t;
            if (idx < 1600) {
                int r = idx >> 4, j = (idx & 15) << 2;
                bf16x4 s;
                #pragma unroll
                for (int i = 0; i < 4; ++i) s[i] = (bf16)qv[p][i];
                *(bf16x4*)&Abuf[r * LSA + j] = s;
            }
        }
        // per-chunk W fragments (8 VGPRs, L2-hot); issued pre-barrier, drains at barrier
        bf16x8 wf0 = *(const bf16x8*)(Wt + rB * CC + kc * 64 + hi8);
        bf16x8 wf1 = *(const bf16x8*)(Wt + rB * CC + kc * 64 + 32 + hi8);
        f32x4 qn[4];
        if (kc < 3) {                          // prefetch next chunk; drains under MFMA+barrier
            #pragma unroll
            for (int p = 0; p < 4; ++p) {
                int idx = p * 512 + t;
                if (idx < 1600) {
                    int r = idx >> 4, j = (idx & 15) << 2;
                    qn[p] = *(const f32x4*)(qb + r * CC + (kc + 1) * 64 + j);
                }
            }
        }
        __syncthreads();                       // Abuf ready

        if (w < 7) {
            #pragma unroll
            for (int I = 0; I < 7; ++I) {
                int row = I * 16 + ln16;
                row = (row < NN) ? row : (NN - 1);   // clamp: rows>=100 discarded
                bf16x8 av = *(const bf16x8*)&Abuf[row * LSA + hi8];
                acc1[I] = __builtin_amdgcn_mfma_f32_16x16x32_bf16(av, wf0, acc1[I], 0, 0, 0);
            }
            #pragma unroll
            for (int I = 0; I < 7; ++I) {
                int row = I * 16 + ln16;
                row = (row < NN) ? row : (NN - 1);
                bf16x8 av = *(const bf16x8*)&Abuf[row * LSA + 32 + hi8];
                acc1[I] = __builtin_amdgcn_mfma_f32_16x16x32_bf16(av, wf1, acc1[I], 0, 0, 0);
            }
        }
        if (kc < 3) {
            #pragma unroll
            for (int p = 0; p < 4; ++p) qv[p] = qn[p];
        }
    }
    // no barrier here: epilogue writes PW/DW (disjoint from Abuf); visibility via the sync below.

    // epilogue A: zero PW k-pad cols (must be exact 0), write pw (bf16) / dw (fp32)
    for (int i = t; i < NN * 28; i += 512) {
        int r = i / 28, m = 100 + (i - (i / 28) * 28);
        PW[r * LDPW + m] = (bf16)0.f;
    }
    // prefetch value loads for ks=0 (latency hides under epilogue + barrier)
    float xv[8], yv[8];
    #pragma unroll
    for (int j = 0; j < 8; ++j) {
        int m = hi8 + j;                       // ks=0: m < 32 < NN always
        const float* vr = vb + m * CC;
        xv[j] = vr[cb];
        yv[j] = vr[cb + 128];
    }
    if (w < 7) {
        const int kap = w * 16 + ln16;
        const float bw = (kap < NKK) ? bwl[kap] : 0.f;
        #pragma unroll
        for (int I = 0; I < 7; ++I) {
            #pragma unroll
            for (int r = 0; r < 4; ++r) {
                int n = I * 16 + g * 4 + r;
                if (n < NN && kap < NKK) {
                    float v = acc1[I][r] + bw;
                    if (kap < 3) DW[n][kap] = v;
                    else         PW[n * LDPW + (kap - 3)] = (bf16)v;
                }
            }
        }
    }
    __syncthreads();   // PW/DW visible

    // ---------------- Phase B/C: conv (batched loads, single drain) + GEMM2 ----------------
    f32x4 acc2[2][7];
    #pragma unroll
    for (int st = 0; st < 2; ++st)
        #pragma unroll
        for (int I = 0; I < 7; ++I) acc2[st][I] = (f32x4){0.f, 0.f, 0.f, 0.f};

    #pragma unroll
    for (int ks = 0; ks < 4; ++ks) {
        if (ks) {   // batch all 16 value loads for this ks, one drain
            #pragma unroll
            for (int j = 0; j < 8; ++j) {
                int m = ks * 32 + hi8 + j;
                bool mv = (m < NN);
                const float* vr = vb + m * CC;
                xv[j] = mv ? vr[cb]       : 0.f;
                yv[j] = mv ? vr[cb + 128] : 0.f;
            }
        }
        bf16x8 dv0, dv1;
        #pragma unroll
        for (int j = 0; j < 8; ++j) {
            int  m  = ks * 32 + hi8 + j;
            bool mv = (m < NN);
            int  mc = mv ? m : (NN - 1);
            float w0 = DW[mc][0], w1 = DW[mc][1], w2 = DW[mc][2];
            float x0 = xv[j], y0 = yv[j];
            float xm = __shfl(x0, (lane - 1) & 63), xp = __shfl(x0, (lane + 1) & 63);
            float ym = __shfl(y0, (lane - 1) & 63), yp = __shfl(y0, (lane + 1) & 63);
            if (ln16 == 0) {
                xm = (mv && cb > 0) ? vb[m * CC + cb - 1] : 0.f;
                ym = mv ? vb[m * CC + cb + 127] : 0.f;
            }
            if (ln16 == 15) {
                xp = mv ? vb[m * CC + cb + 1] : 0.f;
                yp = (mv && cb + 129 < CC) ? vb[m * CC + cb + 129] : 0.f;
            }
            float d0 = w0 * xm + w1 * x0 + w2 * xp;
            float d1 = w0 * ym + w1 * y0 + w2 * yp;
            dv0[j] = (bf16)(mv ? fmaxf(d0, 0.f) : 0.f);
            dv1[j] = (bf16)(mv ? fmaxf(d1, 0.f) : 0.f);
        }
        #pragma unroll
        for (int I = 0; I < 7; ++I) {
            int row = I * 16 + ln16;
            row = (row < NN) ? row : (NN - 1);   // PW has 100 rows; clamped rows discarded
            bf16x8 af = *(const bf16x8*)&PW[row * LDPW + ks * 32 + hi8];
            acc2[0][I] = __builtin_amdgcn_mfma_f32_16x16x32_bf16(af, dv0, acc2[0][I], 0, 0, 0);
            acc2[1][I] = __builtin_amdgcn_mfma_f32_16x16x32_bf16(af, dv1, acc2[1][I], 0, 0, 0);
        }
    }

    // LN affine params (L2-hot)
    const float gm0 = gamma[cb], gm1 = gamma[cb + 128];
    const float bt0 = beta[cb],  bt1 = beta[cb + 128];

    // ---------------- Phase D: LayerNorm ----------------
    #pragma unroll
    for (int I = 0; I < 7; ++I) {
        #pragma unroll
        for (int r = 0; r < 4; ++r) {
            float a = acc2[0][I][r], e = acc2[1][I][r];
            float s1 = a + e, s2 = a * a + e * e;
            #pragma unroll
            for (int mk = 1; mk < 16; mk <<= 1) {
                s1 += __shfl_xor(s1, mk);
                s2 += __shfl_xor(s2, mk);
            }
            int n = I * 16 + g * 4 + r;
            if (ln16 == 0 && n < NN) {
                RP[w][n][0] = s1;
                RP[w][n][1] = s2;
            }
        }
    }
    __syncthreads();
    if (t < NN) {
        float S1 = 0.f, S2 = 0.f;
        #pragma unroll
        for (int wi = 0; wi < 8; ++wi) { S1 += RP[wi][t][0]; S2 += RP[wi][t][1]; }
        float mu  = S1 * (1.f / 256.f);
        float var = S2 * (1.f / 256.f) - mu * mu;
        RS[t][0] = mu;
        RS[t][1] = rsqrtf(fmaxf(var, 0.f) + 1e-5f);
    }
    __syncthreads();   // after this, all GEMM2 PW reads are done -> OT may alias PW/Abuf

    // normalize + transpose through LDS in 3 chunks of 40 rows
    float* ob = out + (size_t)b * NN * CC;
    #pragma unroll
    for (int h = 0; h < 3; ++h) {
        const int n0   = h * 40;
        const int rows = (h == 2) ? 20 : 40;
        #pragma unroll
        for (int I = 0; I < 7; ++I) {
            #pragma unroll
            for (int r = 0; r < 4; ++r) {
                int n = I * 16 + g * 4 + r;
                if (n >= n0 && n < n0 + rows) {
                    float mu = RS[n][0], rs = RS[n][1];
                    int rt = n - n0;
                    OT[rt * OTS + cb]       = (acc2[0][I][r] - mu) * rs * gm0 + bt0;
                    OT[rt * OTS + cb + 128] = (acc2[1][I][r] - mu) * rs * gm1 + bt1;
                }
            }
        }
        __syncthreads();
        #pragma unroll
        for (int p = 0; p < 5; ++p) {
            int idx = p * 512 + t;              // rows x 64 f32x4
            if (idx < rows * 64) {
                int row = idx >> 6, c4 = (idx & 63) << 2;
                *(f32x4*)(ob + (size_t)(n0 + row) * CC + c4) = *(const f32x4*)&OT[row * OTS + c4];
            }
        }
        if (h < 2) __syncthreads();
    }
}

extern "C" void kernel_launch(void* const* d_in, const int* in_sizes, int n_in,
                              void* d_out, int out_size, void* d_ws, size_t ws_size,
                              hipStream_t stream) {
    const float* query = (const float*)d_in[0];
    const float* value = (const float*)d_in[1];
    const float* W     = (const float*)d_in[2];
    const float* bwl   = (const float*)d_in[3];
    const float* gamma = (const float*)d_in[4];
    const float* beta  = (const float*)d_in[5];
    bf16* Wt = (bf16*)d_ws;   // 103*256*2 = 52736 B

    wl_transpose<<<dim3((NKK * CC + 255) / 256), dim3(256), 0, stream>>>(W, Wt);
    dysepconv_fused<<<dim3(512), dim3(512), 0, stream>>>(query, value, Wt, bwl, gamma, beta, (float*)d_out);
}